// Round 1
// 667.788 us; speedup vs baseline: 1.1059x; 1.1059x over previous
//
#include <hip/hip_runtime.h>
#include <math.h>

// GATGuard: 3-layer GAT, cosine-sim attention (thresh 0.1), L1 row norm,
// exp weights, degree self-loop. fp32 in/out. N=50000, E=800000.
//
// R16: R15 base. proj_act_norm rewritten with register blocking:
// each thread computes 8 rows x 4 output cols (acc[8][4]), float4 LDS
// reads (ds_read_b128 broadcast) + float4 W loads. Old version issued
// 16 scalar ds_read_b32 per 16 FMAs -> 25% of fp32 peak (166us @ D=256,
// VALUBusy 78%, MfmaUtil 0). New: 128 FMAs per 12 mem ops per 4-d step.
// Numerics identical (fp32, same d-order). Att kernels unchanged.

static inline int cdiv(int a, int b){ return (a + b - 1) / b; }

// ---------------- small helpers ----------------

__device__ inline float vdot(float4 a, float4 b){ return a.x*b.x + a.y*b.y + a.z*b.z + a.w*b.w; }
__device__ inline void vfma(float4& acc, float w, float4 b){
  acc.x += w*b.x; acc.y += w*b.y; acc.z += w*b.z; acc.w += w*b.w;
}
__device__ inline float4 vscale(float w, float4 a){ return make_float4(w*a.x, w*a.y, w*a.z, w*a.w); }

__device__ inline float wred(float d){
  #pragma unroll
  for (int off = 32; off; off >>= 1) d += __shfl_xor(d, off);
  return d;
}

__device__ inline unsigned short f2bf(float f){        // RNE float->bf16
  unsigned int u = __float_as_uint(f);
  unsigned int r = (u + 0x7FFFu + ((u >> 16) & 1u)) >> 16;
  return (unsigned short)r;
}
__device__ inline float bf2f(unsigned int us){ return __uint_as_float(us << 16); }

__device__ inline void bf8_to_f(uint4 v, float* f){
  f[0] = bf2f(v.x & 0xFFFFu); f[1] = bf2f(v.x >> 16);
  f[2] = bf2f(v.y & 0xFFFFu); f[3] = bf2f(v.y >> 16);
  f[4] = bf2f(v.z & 0xFFFFu); f[5] = bf2f(v.z >> 16);
  f[6] = bf2f(v.w & 0xFFFFu); f[7] = bf2f(v.w >> 16);
}

// ---------------- CSR build (from row[]/col[]) ----------------

__global__ void count_kernel(const int* __restrict__ row, int* __restrict__ cnt, int E){
  int e = blockIdx.x * blockDim.x + threadIdx.x;
  if (e < E) atomicAdd(&cnt[row[e]], 1);
}

__global__ void scan1_kernel(const int* __restrict__ cnt, int* __restrict__ offs,
                             int* __restrict__ bsum, int n){
  __shared__ int tmp[256];
  int tid = threadIdx.x;
  int g = blockIdx.x * 256 + tid;
  int v = (g < n) ? cnt[g] : 0;
  tmp[tid] = v;
  __syncthreads();
  for (int off = 1; off < 256; off <<= 1){
    int t = (tid >= off) ? tmp[tid - off] : 0;
    __syncthreads();
    tmp[tid] += t;
    __syncthreads();
  }
  if (g < n) offs[g] = tmp[tid] - v;          // in-block exclusive
  if (tid == 255) bsum[blockIdx.x] = tmp[255];
}

__global__ void scan2_kernel(int* __restrict__ bsum, int* __restrict__ offs, int nb, int n){
  __shared__ int tmp[256];
  int tid = threadIdx.x;
  int v = (tid < nb) ? bsum[tid] : 0;
  tmp[tid] = v;
  __syncthreads();
  for (int off = 1; off < 256; off <<= 1){
    int t = (tid >= off) ? tmp[tid - off] : 0;
    __syncthreads();
    tmp[tid] += t;
    __syncthreads();
  }
  if (tid < nb) bsum[tid] = tmp[tid] - v;     // exclusive block offsets
  if (tid == 255) offs[n] = tmp[255];         // grand total = E
}

__global__ void scan3_kernel(int* __restrict__ offs, int* __restrict__ cur,
                             const int* __restrict__ bsum, int n){
  int g = blockIdx.x * 256 + threadIdx.x;
  if (g < n){
    int o = offs[g] + bsum[blockIdx.x];
    offs[g] = o;
    cur[g]  = o;
  }
}

__global__ void scatter_kernel(const int* __restrict__ row, const int* __restrict__ col,
                               int* __restrict__ cur, int* __restrict__ ecol, int E){
  int e = blockIdx.x * blockDim.x + threadIdx.x;
  if (e < E){
    int p = atomicAdd(&cur[row[e]], 1);
    ecol[p] = col[e];
  }
}

// ---------------- layer-0 invnorm (x) ----------------

__global__ void invnorm128_kernel(const float* __restrict__ x, float* __restrict__ invn, int N){
  int n = blockIdx.x * 4 + (threadIdx.x >> 6);
  int lane = threadIdx.x & 63;
  if (n >= N) return;
  float2 a = ((const float2*)(x + (size_t)n * 128))[lane];
  float ss = a.x * a.x + a.y * a.y;
  ss = wred(ss);
  if (lane == 0) invn[n] = 1.0f / fmaxf(sqrtf(ss), 1e-12f);
}

// ---------------- D=128 (L0): half-wave float4 engines, fp32 (R12) ----------------

template<int R>
__global__ void att_agg_wave128(const float* __restrict__ x, const float* __restrict__ invn,
                                const int* __restrict__ offs, const int* __restrict__ ecol,
                                float* __restrict__ out, int N){
  constexpr int LT = 64;
  __shared__ float tls[4][LT];
  __shared__ int   tlk[4][LT];
  const int wid  = threadIdx.x >> 6;            // 0..1
  const int lane = threadIdx.x & 63;
  const int half = lane >> 5, hl = lane & 31;
  const int hidx = wid * 2 + half;              // 0..3
  const int n = blockIdx.x * 2 + wid;
  if (n >= N) return;
  const int s = offs[n], e = offs[n + 1];
  const float inr = invn[n];
  const float4* xv = (const float4*)x;          // row stride = 32 float4s
  float4 a = xv[(size_t)n * 32 + hl];

  float4 br[R];
  float  simv[R];
  float  rowsum = 0.0f;
  int    deg = 0;

  #pragma unroll
  for (int r = 0; r < R; r++){
    simv[r] = 0.0f;
    int k = s + 2 * r + half;
    if (k < e){
      int c = ecol[k];
      float4 b = xv[(size_t)c * 32 + hl];
      br[r] = b;
      float d = vdot(a, b);
      #pragma unroll
      for (int off = 16; off; off >>= 1) d += __shfl_xor(d, off);
      d *= inr * invn[c];
      if (d < 0.1f) d = 0.0f;
      simv[r] = d;
      rowsum += d;
      deg += (d != 0.0f) ? 1 : 0;
    }
  }

  int tc = 0, kover = e;
  int k = s + 2 * R + half;
  for (; k + 2 < e; k += 4){
    int c0 = ecol[k], c1 = ecol[k + 2];
    float4 b0 = xv[(size_t)c0 * 32 + hl];
    float4 b1 = xv[(size_t)c1 * 32 + hl];
    float d0 = vdot(a, b0), d1 = vdot(a, b1);
    #pragma unroll
    for (int off = 16; off; off >>= 1){ d0 += __shfl_xor(d0, off); d1 += __shfl_xor(d1, off); }
    d0 *= inr * invn[c0];
    d1 *= inr * invn[c1];
    if (d0 < 0.1f) d0 = 0.0f;
    if (d1 < 0.1f) d1 = 0.0f;
    rowsum += d0 + d1;
    deg += (d0 != 0.0f) + (d1 != 0.0f);
    if (d0 > 0.0f){
      if (tc < LT){ if (hl == 0){ tls[hidx][tc] = d0; tlk[hidx][tc] = c0; } tc++; }
      else if (kover > k) kover = k;
    }
    if (d1 > 0.0f){
      if (tc < LT){ if (hl == 0){ tls[hidx][tc] = d1; tlk[hidx][tc] = c1; } tc++; }
      else if (kover > k + 2) kover = k + 2;
    }
  }
  if (k < e){
    int c0 = ecol[k];
    float4 b0 = xv[(size_t)c0 * 32 + hl];
    float d0 = vdot(a, b0);
    #pragma unroll
    for (int off = 16; off; off >>= 1) d0 += __shfl_xor(d0, off);
    d0 *= inr * invn[c0];
    if (d0 < 0.1f) d0 = 0.0f;
    rowsum += d0;
    deg += (d0 != 0.0f) ? 1 : 0;
    if (d0 > 0.0f){
      if (tc < LT){ if (hl == 0){ tls[hidx][tc] = d0; tlk[hidx][tc] = c0; } tc++; }
      else if (kover > k) kover = k;
    }
  }

  rowsum += __shfl_xor(rowsum, 32);
  deg    += __shfl_xor(deg, 32);
  const float invrs = (rowsum > 0.0f) ? 1.0f / rowsum : 0.0f;
  const float wself = expf(1.0f / (float)(deg + 1));

  float4 acc = (half == 0) ? vscale(wself, a) : make_float4(0.f, 0.f, 0.f, 0.f);
  #pragma unroll
  for (int r = 0; r < R; r++){
    if (simv[r] > 0.0f) vfma(acc, expf(simv[r] * invrs), br[r]);
  }
  int j = 0;
  for (; j + 1 < tc; j += 2){
    float w0 = expf(tls[hidx][j] * invrs);
    float w1 = expf(tls[hidx][j + 1] * invrs);
    int c0 = tlk[hidx][j], c1 = tlk[hidx][j + 1];
    float4 b0 = xv[(size_t)c0 * 32 + hl];
    float4 b1 = xv[(size_t)c1 * 32 + hl];
    vfma(acc, w0, b0);
    vfma(acc, w1, b1);
  }
  if (j < tc){
    float w0 = expf(tls[hidx][j] * invrs);
    float4 b0 = xv[(size_t)tlk[hidx][j] * 32 + hl];
    vfma(acc, w0, b0);
  }
  for (int k2 = kover; k2 < e; k2 += 2){
    int c = ecol[k2];
    float4 b = xv[(size_t)c * 32 + hl];
    float d = vdot(a, b);
    #pragma unroll
    for (int off = 16; off; off >>= 1) d += __shfl_xor(d, off);
    d *= inr * invn[c];
    if (d >= 0.1f) vfma(acc, expf(d * invrs), b);
  }

  acc.x += __shfl_xor(acc.x, 32);
  acc.y += __shfl_xor(acc.y, 32);
  acc.z += __shfl_xor(acc.z, 32);
  acc.w += __shfl_xor(acc.w, 32);
  if (half == 0) ((float4*)out)[(size_t)n * 32 + hl] = acc;
}

// ---------------- L1: bf16-row att (sims + aggregation), half-wave engines ----------------
// Rows are 256 bf16 = 512B; each half-engine (32 lanes x 16B) holds a full row.
// R cached rows per half stored as uint4; fp32 accumulation; fp32 output.

template<int R>
__global__ void att256_bf(const unsigned short* __restrict__ hbf,
                          const float* __restrict__ invn,
                          const int* __restrict__ offs, const int* __restrict__ ecol,
                          float* __restrict__ out, int N){
  constexpr int LT = 64;
  __shared__ float tls[4][LT];
  __shared__ int   tlk[4][LT];
  const int wid  = threadIdx.x >> 6;            // 0..1
  const int lane = threadIdx.x & 63;
  const int half = lane >> 5, hl = lane & 31;
  const int hidx = wid * 2 + half;              // 0..3
  const int n = blockIdx.x * 2 + wid;
  if (n >= N) return;
  const int s = offs[n], e = offs[n + 1];
  const float inr = invn[n];
  const uint4* hb = (const uint4*)hbf;          // row = 32 uint4

  float a8[8];
  bf8_to_f(hb[(size_t)n * 32 + hl], a8);

  uint4 brv[R];
  float simv[R];
  float rowsum = 0.0f;
  int   deg = 0;

  // cached slots: edge k = s + 2r + half
  #pragma unroll
  for (int r = 0; r < R; r++){
    simv[r] = 0.0f;
    int k = s + 2 * r + half;
    if (k < e){
      int c = ecol[k];
      uint4 v = hb[(size_t)c * 32 + hl];
      brv[r] = v;
      float b8[8]; bf8_to_f(v, b8);
      float d = 0.0f;
      #pragma unroll
      for (int t = 0; t < 8; t++) d += a8[t] * b8[t];
      #pragma unroll
      for (int off = 16; off; off >>= 1) d += __shfl_xor(d, off);
      d *= inr * invn[c];
      if (d < 0.1f) d = 0.0f;
      simv[r] = d;
      rowsum += d;
      deg += (d != 0.0f) ? 1 : 0;
    }
  }

  // dynamic tail: this half's edges stride 2, two in flight
  int tc = 0, kover = e;
  int k = s + 2 * R + half;
  for (; k + 2 < e; k += 4){
    int c0 = ecol[k], c1 = ecol[k + 2];
    uint4 v0 = hb[(size_t)c0 * 32 + hl];
    uint4 v1 = hb[(size_t)c1 * 32 + hl];
    float b0[8], b1[8];
    bf8_to_f(v0, b0);
    bf8_to_f(v1, b1);
    float d0 = 0.0f, d1 = 0.0f;
    #pragma unroll
    for (int t = 0; t < 8; t++){ d0 += a8[t] * b0[t]; d1 += a8[t] * b1[t]; }
    #pragma unroll
    for (int off = 16; off; off >>= 1){ d0 += __shfl_xor(d0, off); d1 += __shfl_xor(d1, off); }
    d0 *= inr * invn[c0];
    d1 *= inr * invn[c1];
    if (d0 < 0.1f) d0 = 0.0f;
    if (d1 < 0.1f) d1 = 0.0f;
    rowsum += d0 + d1;
    deg += (d0 != 0.0f) + (d1 != 0.0f);
    if (d0 > 0.0f){
      if (tc < LT){ if (hl == 0){ tls[hidx][tc] = d0; tlk[hidx][tc] = c0; } tc++; }
      else if (kover > k) kover = k;
    }
    if (d1 > 0.0f){
      if (tc < LT){ if (hl == 0){ tls[hidx][tc] = d1; tlk[hidx][tc] = c1; } tc++; }
      else if (kover > k + 2) kover = k + 2;
    }
  }
  if (k < e){
    int c0 = ecol[k];
    uint4 v0 = hb[(size_t)c0 * 32 + hl];
    float b0[8]; bf8_to_f(v0, b0);
    float d0 = 0.0f;
    #pragma unroll
    for (int t = 0; t < 8; t++) d0 += a8[t] * b0[t];
    #pragma unroll
    for (int off = 16; off; off >>= 1) d0 += __shfl_xor(d0, off);
    d0 *= inr * invn[c0];
    if (d0 < 0.1f) d0 = 0.0f;
    rowsum += d0;
    deg += (d0 != 0.0f) ? 1 : 0;
    if (d0 > 0.0f){
      if (tc < LT){ if (hl == 0){ tls[hidx][tc] = d0; tlk[hidx][tc] = c0; } tc++; }
      else if (kover > k) kover = k;
    }
  }

  // merge halves
  rowsum += __shfl_xor(rowsum, 32);
  deg    += __shfl_xor(deg, 32);
  const float invrs = (rowsum > 0.0f) ? 1.0f / rowsum : 0.0f;
  const float wself = expf(1.0f / (float)(deg + 1));

  // phase B: fp32 accumulation over bf16 rows
  float acc8[8];
  #pragma unroll
  for (int t = 0; t < 8; t++) acc8[t] = (half == 0) ? wself * a8[t] : 0.0f;
  #pragma unroll
  for (int r = 0; r < R; r++){
    if (simv[r] > 0.0f){
      float w = expf(simv[r] * invrs);
      float b8[8]; bf8_to_f(brv[r], b8);
      #pragma unroll
      for (int t = 0; t < 8; t++) acc8[t] += w * b8[t];
    }
  }
  int j = 0;
  for (; j + 1 < tc; j += 2){
    float w0 = expf(tls[hidx][j] * invrs);
    float w1 = expf(tls[hidx][j + 1] * invrs);
    uint4 v0 = hb[(size_t)tlk[hidx][j] * 32 + hl];
    uint4 v1 = hb[(size_t)tlk[hidx][j + 1] * 32 + hl];
    float b0[8], b1[8];
    bf8_to_f(v0, b0);
    bf8_to_f(v1, b1);
    #pragma unroll
    for (int t = 0; t < 8; t++) acc8[t] += w0 * b0[t] + w1 * b1[t];
  }
  if (j < tc){
    float w0 = expf(tls[hidx][j] * invrs);
    uint4 v0 = hb[(size_t)tlk[hidx][j] * 32 + hl];
    float b0[8]; bf8_to_f(v0, b0);
    #pragma unroll
    for (int t = 0; t < 8; t++) acc8[t] += w0 * b0[t];
  }
  // overflow (deg > 2R + 2*LT only): recompute this half's edges (stride 2)
  for (int k2 = kover; k2 < e; k2 += 2){
    int c = ecol[k2];
    uint4 v = hb[(size_t)c * 32 + hl];
    float b[8]; bf8_to_f(v, b);
    float d = 0.0f;
    #pragma unroll
    for (int t = 0; t < 8; t++) d += a8[t] * b[t];
    #pragma unroll
    for (int off = 16; off; off >>= 1) d += __shfl_xor(d, off);
    d *= inr * invn[c];
    if (d >= 0.1f){
      float w = expf(d * invrs);
      #pragma unroll
      for (int t = 0; t < 8; t++) acc8[t] += w * b[t];
    }
  }

  // merge halves, store fp32 (lane hl owns elements [hl*8, hl*8+8))
  #pragma unroll
  for (int t = 0; t < 8; t++) acc8[t] += __shfl_xor(acc8[t], 32);
  if (half == 0){
    float4* ov = (float4*)out;
    ov[(size_t)n * 64 + 2 * hl]     = make_float4(acc8[0], acc8[1], acc8[2], acc8[3]);
    ov[(size_t)n * 64 + 2 * hl + 1] = make_float4(acc8[4], acc8[5], acc8[6], acc8[7]);
  }
}

// ---------------- layer 2: bf16 sims on h2, aggregate z2 (16-d fp32) ----------------

__global__ void att_z16_bf(const unsigned short* __restrict__ hbf,
                           const float* __restrict__ invn,
                           const int* __restrict__ offs, const int* __restrict__ ecol,
                           const float* __restrict__ z2, float* __restrict__ out, int N){
  constexpr int LT = 64;
  __shared__ float tls[4][LT];
  __shared__ int   tlk[4][LT];
  const int wid  = threadIdx.x >> 6;            // 0..1
  const int lane = threadIdx.x & 63;
  const int half = lane >> 5, hl = lane & 31;
  const int hidx = wid * 2 + half;              // 0..3
  const int n = blockIdx.x * 2 + wid;
  if (n >= N) return;
  const int s = offs[n], e = offs[n + 1];
  const float inr = invn[n];
  const uint4* hb = (const uint4*)hbf;          // row = 32 uint4

  float a8[8];
  bf8_to_f(hb[(size_t)n * 32 + hl], a8);

  float rowsum = 0.0f;
  int   deg = 0;
  int   tc = 0, kover = e;

  int k = s + half;
  for (; k + 2 < e; k += 4){
    int c0 = ecol[k], c1 = ecol[k + 2];
    uint4 v0 = hb[(size_t)c0 * 32 + hl];
    uint4 v1 = hb[(size_t)c1 * 32 + hl];
    float b0[8], b1[8];
    bf8_to_f(v0, b0);
    bf8_to_f(v1, b1);
    float d0 = 0.0f, d1 = 0.0f;
    #pragma unroll
    for (int t = 0; t < 8; t++){ d0 += a8[t] * b0[t]; d1 += a8[t] * b1[t]; }
    #pragma unroll
    for (int off = 16; off; off >>= 1){ d0 += __shfl_xor(d0, off); d1 += __shfl_xor(d1, off); }
    d0 *= inr * invn[c0];
    d1 *= inr * invn[c1];
    if (d0 < 0.1f) d0 = 0.0f;
    if (d1 < 0.1f) d1 = 0.0f;
    rowsum += d0 + d1;
    deg += (d0 != 0.0f) + (d1 != 0.0f);
    if (d0 > 0.0f){
      if (tc < LT){ if (hl == 0){ tls[hidx][tc] = d0; tlk[hidx][tc] = c0; } tc++; }
      else if (kover > k) kover = k;
    }
    if (d1 > 0.0f){
      if (tc < LT){ if (hl == 0){ tls[hidx][tc] = d1; tlk[hidx][tc] = c1; } tc++; }
      else if (kover > k + 2) kover = k + 2;
    }
  }
  if (k < e){
    int c0 = ecol[k];
    uint4 v0 = hb[(size_t)c0 * 32 + hl];
    float b0[8]; bf8_to_f(v0, b0);
    float d0 = 0.0f;
    #pragma unroll
    for (int t = 0; t < 8; t++) d0 += a8[t] * b0[t];
    #pragma unroll
    for (int off = 16; off; off >>= 1) d0 += __shfl_xor(d0, off);
    d0 *= inr * invn[c0];
    if (d0 < 0.1f) d0 = 0.0f;
    rowsum += d0;
    deg += (d0 != 0.0f) ? 1 : 0;
    if (d0 > 0.0f){
      if (tc < LT){ if (hl == 0){ tls[hidx][tc] = d0; tlk[hidx][tc] = c0; } tc++; }
      else if (kover > k) kover = k;
    }
  }

  rowsum += __shfl_xor(rowsum, 32);
  deg    += __shfl_xor(deg, 32);
  const float invrs = (rowsum > 0.0f) ? 1.0f / rowsum : 0.0f;
  const float wself = expf(1.0f / (float)(deg + 1));

  const int grp = hl >> 4, ch = hl & 15;
  float acc = 0.0f;
  for (int j = grp; j < tc; j += 2){
    float w = expf(tls[hidx][j] * invrs);
    int   c = tlk[hidx][j];
    acc += w * z2[(size_t)c * 16 + ch];
  }
  for (int k2 = kover; k2 < e; k2 += 2){
    int c = ecol[k2];
    uint4 v = hb[(size_t)c * 32 + hl];
    float b[8]; bf8_to_f(v, b);
    float d = 0.0f;
    #pragma unroll
    for (int t = 0; t < 8; t++) d += a8[t] * b[t];
    #pragma unroll
    for (int off = 16; off; off >>= 1) d += __shfl_xor(d, off);
    d *= inr * invn[c];
    if (d >= 0.1f){
      float w = expf(d * invrs);
      if (grp == 0) acc += w * z2[(size_t)c * 16 + ch];
    }
  }
  acc += __shfl_xor(acc, 16);   // merge 2 groups within half
  acc += __shfl_xor(acc, 32);   // merge halves
  if (lane < 16) out[(size_t)n * 16 + lane] = acc + wself * z2[(size_t)n * 16 + lane];
}

// ---------------- projection + leaky-ReLU + invnorm (+ optional bf16 copy) ----------------
// R16: register-blocked. Block = 256 threads, 32 rows. Wave w owns rows
// [n0+8w, n0+8w+8); lane l owns output cols [4l, 4l+4) = head l>>4,
// within-head offset 4*(l&15). acc[8][4]; float4 LDS x-reads (broadcast),
// float4 coalesced W loads. 128 FMAs per 4-d step vs 12 memory ops.

template<int D>
__global__ __launch_bounds__(256) void proj_act_norm(
    const float* __restrict__ xin, const float* __restrict__ W,
    float* __restrict__ hout, float* __restrict__ invn,
    unsigned short* __restrict__ hbf, int N){
  __shared__ float xs[32][D];
  const int tid = threadIdx.x;
  const int w = tid >> 6, l = tid & 63;
  const int n0 = blockIdx.x * 32;

  {
    float4* xs4 = (float4*)&xs[0][0];
    const float4* xin4 = (const float4*)(xin + (size_t)n0 * D);
    const int rows = (N - n0 >= 32) ? 32 : (N - n0);
    const int limit4 = rows * (D / 4);
    constexpr int total4 = 32 * D / 4;
    for (int i = tid; i < total4; i += 256)
      xs4[i] = (i < limit4) ? xin4[i] : make_float4(0.f, 0.f, 0.f, 0.f);
  }
  __syncthreads();

  const int h  = l >> 4;            // head 0..3
  const int oo = (l & 15) * 4;      // out offset within head (16B aligned)
  const float* Wp = W + (size_t)h * D * 64 + oo;
  const float* xrow = &xs[w * 8][0];

  float acc[8][4];
  #pragma unroll
  for (int i = 0; i < 8; i++){
    acc[i][0] = 0.f; acc[i][1] = 0.f; acc[i][2] = 0.f; acc[i][3] = 0.f;
  }

  for (int d = 0; d < D; d += 4){
    float4 w0 = *(const float4*)(Wp + (size_t)(d + 0) * 64);
    float4 w1 = *(const float4*)(Wp + (size_t)(d + 1) * 64);
    float4 w2 = *(const float4*)(Wp + (size_t)(d + 2) * 64);
    float4 w3 = *(const float4*)(Wp + (size_t)(d + 3) * 64);
    #pragma unroll
    for (int i = 0; i < 8; i++){
      float4 xv = *(const float4*)(xrow + i * D + d);
      acc[i][0] += xv.x * w0.x + xv.y * w1.x + xv.z * w2.x + xv.w * w3.x;
      acc[i][1] += xv.x * w0.y + xv.y * w1.y + xv.z * w2.y + xv.w * w3.y;
      acc[i][2] += xv.x * w0.z + xv.y * w1.z + xv.z * w2.z + xv.w * w3.z;
      acc[i][3] += xv.x * w0.w + xv.y * w1.w + xv.z * w2.w + xv.w * w3.w;
    }
  }

  const int nrow = n0 + w * 8;
  #pragma unroll
  for (int i = 0; i < 8; i++){
    #pragma unroll
    for (int j = 0; j < 4; j++){
      float a = acc[i][j];
      acc[i][j] = (a > 0.0f) ? a : 0.01f * a;   // leaky relu
    }
    float ss = acc[i][0]*acc[i][0] + acc[i][1]*acc[i][1]
             + acc[i][2]*acc[i][2] + acc[i][3]*acc[i][3];
    ss = wred(ss);
    const int n = nrow + i;
    if (n < N){
      if (l == 0) invn[n] = 1.0f / fmaxf(sqrtf(ss), 1e-12f);
      ((float4*)hout)[(size_t)n * 64 + l] =
          make_float4(acc[i][0], acc[i][1], acc[i][2], acc[i][3]);
      if (hbf){
        ushort4 u;
        u.x = f2bf(acc[i][0]); u.y = f2bf(acc[i][1]);
        u.z = f2bf(acc[i][2]); u.w = f2bf(acc[i][3]);
        ((ushort4*)hbf)[(size_t)n * 64 + l] = u;
      }
    }
  }
}

__global__ void proj16_kernel(const float* __restrict__ x, const float* __restrict__ W,
                              float* __restrict__ z, int N){
  __shared__ float xs[16][256];   // 16 KB
  __shared__ float wsh[256 * 16]; // 16 KB
  int tid = threadIdx.x;
  int n0 = blockIdx.x * 16;
  for (int i = tid; i < 16 * 256; i += 256){
    int nl = i >> 8, d = i & 255;
    int n = n0 + nl;
    xs[nl][d] = (n < N) ? x[(size_t)n * 256 + d] : 0.0f;
  }
  for (int i = tid; i < 256 * 16; i += 256) wsh[i] = W[i];
  __syncthreads();
  int nl = tid >> 4, o = tid & 15;
  float acc = 0.0f;
  for (int d = 0; d < 256; d++) acc += xs[nl][d] * wsh[d * 16 + o];
  int n = n0 + nl;
  if (n < N) z[(size_t)n * 16 + o] = acc;
}

// ---------------- launch ----------------

extern "C" void kernel_launch(void* const* d_in, const int* in_sizes, int n_in,
                              void* d_out, int out_size, void* d_ws, size_t ws_size,
                              hipStream_t stream){
  const float* x  = (const float*)d_in[0];
  const float* W0 = (const float*)d_in[1];
  const float* W1 = (const float*)d_in[2];
  const float* W2 = (const float*)d_in[3];
  const int*   row = (const int*)d_in[4];
  const int*   col = (const int*)d_in[5];
  const int N = in_sizes[0] / 128;
  const int E = in_sizes[4];
  float* out = (float*)d_out;

  // workspace carve-up (~122 MB)
  float* p = (float*)d_ws;
  float* hbuf   = p; p += (size_t)N * 256;
  float* aggbuf = p; p += (size_t)N * 256;
  float* z2     = p; p += (size_t)N * 16;
  float* invn   = p; p += N;
  unsigned short* hbf = (unsigned short*)p; p += (size_t)N * 128;  // N*256 bf16
  int* cnt  = (int*)p;
  int* offs = cnt + N;
  int* cur  = offs + N + 1;
  int* ecol = cur + N;
  int* bsum = ecol + E;

  const int NB = cdiv(N, 256);

  // ---- CSR build (row/col static per call) ----
  hipMemsetAsync(cnt, 0, sizeof(int) * N, stream);
  count_kernel<<<cdiv(E, 256), 256, 0, stream>>>(row, cnt, E);
  scan1_kernel<<<NB, 256, 0, stream>>>(cnt, offs, bsum, N);
  scan2_kernel<<<1, 256, 0, stream>>>(bsum, offs, NB, N);
  scan3_kernel<<<NB, 256, 0, stream>>>(offs, cur, bsum, N);
  scatter_kernel<<<cdiv(E, 256), 256, 0, stream>>>(row, col, cur, ecol, E);

  // ---- Layer 0: fp32 sims on x (D=128), aggregate x, project W0 (+bf16 h1) ----
  invnorm128_kernel<<<cdiv(N, 4), 256, 0, stream>>>(x, invn, N);
  att_agg_wave128<8><<<cdiv(N, 2), 128, 0, stream>>>(x, invn, offs, ecol, aggbuf, N);
  proj_act_norm<128><<<cdiv(N, 32), 256, 0, stream>>>(aggbuf, W0, hbuf, invn, hbf, N);

  // ---- Layer 1: bf16 sims + aggregation on h1, project W1 (+bf16 h2, reuse hbf) ----
  att256_bf<4><<<cdiv(N, 2), 128, 0, stream>>>(hbf, invn, offs, ecol, aggbuf, N);
  proj_act_norm<256><<<cdiv(N, 32), 256, 0, stream>>>(aggbuf, W1, hbuf, invn, hbf, N);

  // ---- Layer 2: z2 = h2.W2 (16-d), bf16 sims on h2, aggregate z2 -> out ----
  proj16_kernel<<<cdiv(N, 16), 256, 0, stream>>>(hbuf, W2, z2, N);
  att_z16_bf<<<cdiv(N, 2), 128, 0, stream>>>(hbf, invn, offs, ecol, z2, out, N);
}